// Round 5
// baseline (240.371 us; speedup 1.0000x reference)
//
#include <hip/hip_runtime.h>

#define NUM_SEGS 1024
#define CHUNK_LOG 13
#define CHUNK (1 << CHUNK_LOG)   // 8192 elements per chunk
#define SUBCH 4                  // chunks per block (superchunk = 32768)
#define SUPER (CHUNK * SUBCH)
#define BLK 512                  // 8 waves/block; grid 512 -> 2 blocks/CU
#define NWAVE (BLK / 64)
#define NBATCH 16                // per-thread batches (1 float4-triple each)
#define SEGBLK 256

__device__ __forceinline__ float waveReduceSumF(float v) {
#pragma unroll
    for (int off = 32; off > 0; off >>= 1) v += __shfl_down(v, off, 64);
    return v;
}
__device__ __forceinline__ double waveReduceSumD(double v) {
#pragma unroll
    for (int off = 32; off > 0; off >>= 1) v += __shfl_down(v, off, 64);
    return v;
}
__device__ __forceinline__ unsigned waveReduceSumU(unsigned v) {
#pragma unroll
    for (int off = 32; off > 0; off >>= 1) v += __shfl_down(v, off, 64);
    return v;
}
__device__ __forceinline__ int waveReduceMaxI(int v) {
#pragma unroll
    for (int off = 32; off > 0; off >>= 1) {
        const int o = __shfl_down(v, off, 64);
        v = o > v ? o : v;
    }
    return v;
}

// ---------------- init: zero accumulators (ws is poisoned 0xAA every call) ---
__global__ void init_kernel(unsigned* __restrict__ seg_cnt,
                            float* __restrict__ csums, int nChunks,
                            unsigned* __restrict__ obs,
                            double* __restrict__ loss1,
                            double* __restrict__ loss2,
                            unsigned* __restrict__ done) {
    const int t = blockIdx.x * blockDim.x + threadIdx.x;
    if (t < NUM_SEGS) seg_cnt[t] = 0u;
    if (t < nChunks) csums[t] = 0.f;
    if (t == 0) { obs[0] = 0u; loss1[0] = 0.0; loss2[0] = 0.0; done[0] = 0u; }
}

// ---------------- pass 1: explicitly software-pipelined streaming ------------
// 16 batches/thread (1 float4+int4+int4 triple each). Depth-2 pipeline: batch
// b+1's 3 loads are ISSUED before batch b is processed, pinned by
// sched_barrier(0) so the compiler cannot sink them. Double-buffer registers
// indexed by compile-time (b&1) inside #pragma unroll -> stays in VGPRs.
__global__ __launch_bounds__(BLK, 4) void pass1_kernel(
    const float* __restrict__ outs, const int* __restrict__ te,
    const int* __restrict__ tt, int N, int nChunks,
    float* __restrict__ csums, unsigned* __restrict__ seg_cnt,
    unsigned* __restrict__ obs, double* __restrict__ loss1) {
    __shared__ unsigned hist[NUM_SEGS];
    __shared__ float redF[NWAVE];
    __shared__ unsigned redU[NWAVE];

    for (int t = threadIdx.x; t < NUM_SEGS; t += BLK) hist[t] = 0u;
    __syncthreads();

    const int lane = threadIdx.x & 63;
    const int wid = threadIdx.x >> 6;
    const int superBase = blockIdx.x * SUPER;

    float sE[SUBCH] = {0.f, 0.f, 0.f, 0.f};  // static-indexed (b>>2 in unroll)
    float sumOE = 0.f;
    unsigned cntE = 0u;

    if (superBase + SUPER <= N) {
        const int i0 = superBase + ((int)threadIdx.x << 2);
        float4 ocb[2];
        int4 ecb[2], scb[2];

#define LOADB(b, sl)                                                        \
    do {                                                                    \
        const int _i = i0 + (b) * (BLK * 4);                                \
        ocb[sl] = *reinterpret_cast<const float4*>(outs + _i);              \
        ecb[sl] = *reinterpret_cast<const int4*>(te + _i);                  \
        scb[sl] = *reinterpret_cast<const int4*>(tt + _i);                  \
    } while (0)

        LOADB(0, 0);
#pragma unroll
        for (int b = 0; b < NBATCH; ++b) {
            if (b + 1 < NBATCH) LOADB(b + 1, (b + 1) & 1);
            __builtin_amdgcn_sched_barrier(0);  // pin: loads b+1 before process b
            {
                const int sl = b & 1;
                const float4 o = ocb[sl];
                const int4 ev = ecb[sl];
                const int4 sv = scb[sl];
                sE[b >> 2] += (__expf(o.x) + __expf(o.y)) +
                              (__expf(o.z) + __expf(o.w));
                const int s0 = sv.x < 0 ? -sv.x : sv.x;
                const int s1 = sv.y < 0 ? -sv.y : sv.y;
                const int s2 = sv.z < 0 ? -sv.z : sv.z;
                const int s3 = sv.w < 0 ? -sv.w : sv.w;
                if (ev.x > 0) { cntE++; sumOE += o.x; atomicAdd(&hist[s0], 1u); }
                if (ev.y > 0) { cntE++; sumOE += o.y; atomicAdd(&hist[s1], 1u); }
                if (ev.z > 0) { cntE++; sumOE += o.z; atomicAdd(&hist[s2], 1u); }
                if (ev.w > 0) { cntE++; sumOE += o.w; atomicAdd(&hist[s3], 1u); }
            }
        }
#undef LOADB

        // per-wave chunk-sum flush: one float atomic per (wave, chunk)
        const int c0 = superBase >> CHUNK_LOG;
#pragma unroll
        for (int k = 0; k < SUBCH; ++k) {
            const float w = waveReduceSumF(sE[k]);
            if (lane == 0) atomicAdd(&csums[c0 + k], w);
        }
    } else {
        // tail path (not hit for N = 16M)
        for (int k = 0; k < SUBCH; ++k) {
            const int cbase = superBase + k * CHUNK;
            if (cbase >= N) break;
            const int end = (cbase + CHUNK < N) ? cbase + CHUNK : N;
            float s = 0.f;
            for (int i = cbase + (int)threadIdx.x; i < end; i += BLK) {
                const float o = outs[i];
                const int e = te[i];
                int sg = tt[i]; sg = sg < 0 ? -sg : sg;
                s += __expf(o);
                if (e > 0) { cntE++; sumOE += o; atomicAdd(&hist[sg], 1u); }
            }
            const float w = waveReduceSumF(s);
            if (lane == 0 && w != 0.f) atomicAdd(&csums[cbase >> CHUNK_LOG], w);
        }
    }

    __syncthreads();  // the only block barrier: hist complete

    for (int t = threadIdx.x; t < NUM_SEGS; t += BLK) {
        const unsigned h = hist[t];
        if (h) atomicAdd(&seg_cnt[t], h);
    }

    // block-reduce E stats
    const float wOE = waveReduceSumF(sumOE);
    const unsigned wC = waveReduceSumU(cntE);
    if (lane == 0) { redF[wid] = wOE; redU[wid] = wC; }
    __syncthreads();
    if (threadIdx.x == 0) {
        float oe = 0.f; unsigned c = 0u;
#pragma unroll
        for (int j = 0; j < NWAVE; ++j) { oe += redF[j]; c += redU[j]; }
        atomicAdd(loss1, (double)oe);
        atomicAdd(obs, c);
    }
}

// ---------------- pass 2 (fused): backward last-idx search + prefix + finalize
// Block t: scan chunks from the end until segment t is found (random data:
// always the last chunk, L2-hot for all 1024 blocks). Then fp64 prefix over
// csums[0..c), fp32 in-chunk exp-sum to LI, V*cnt, ticket-finalize.
__global__ __launch_bounds__(SEGBLK) void seg_final_kernel(
    const float* __restrict__ outs, const int* __restrict__ tt,
    const float* __restrict__ csums, const unsigned* __restrict__ seg_cnt,
    const double* __restrict__ loss1, double* __restrict__ loss2,
    const unsigned* __restrict__ obs, unsigned* __restrict__ done,
    float* __restrict__ out, int N, int nChunks) {
    __shared__ double redD[SEGBLK / 64];
    __shared__ float redF[SEGBLK / 64];
    __shared__ int redI[SEGBLK / 64];
    __shared__ int s_li;

    const int t = blockIdx.x;
    const unsigned cnt = seg_cnt[t];
    const int lane = threadIdx.x & 63, wid = threadIdx.x >> 6;

    if (cnt != 0u) {  // cnt==0 segments contribute 0
        // ---- backward search for the last occurrence of segment t ----
        int c = nChunks - 1;
        int LI = -1;
        for (;;) {
            const int base = c << CHUNK_LOG;
            const int end = (base + CHUNK < N) ? base + CHUNK : N;
            const int span = end - base;
            const int qspan = span & ~3;  // int4-aligned portion
            int li = -1;
            for (int i = base + ((int)threadIdx.x << 2); i < base + qspan;
                 i += SEGBLK * 4) {
                const int4 sv = *reinterpret_cast<const int4*>(tt + i);
                const int s0 = sv.x < 0 ? -sv.x : sv.x;
                const int s1 = sv.y < 0 ? -sv.y : sv.y;
                const int s2 = sv.z < 0 ? -sv.z : sv.z;
                const int s3 = sv.w < 0 ? -sv.w : sv.w;
                if (s3 == t) li = i + 3;
                else if (s2 == t) li = i + 2;
                else if (s1 == t) li = i + 1;
                else if (s0 == t) li = i;
                // ascending i => later assignment always larger
            }
            for (int i = base + qspan + (int)threadIdx.x; i < end; i += SEGBLK) {
                int s = tt[i]; s = s < 0 ? -s : s;
                if (s == t && i > li) li = i;
            }
            li = waveReduceMaxI(li);
            if (lane == 0) redI[wid] = li;
            __syncthreads();
            if (threadIdx.x == 0) {
                int m = redI[0];
#pragma unroll
                for (int j = 1; j < SEGBLK / 64; ++j) m = redI[j] > m ? redI[j] : m;
                s_li = m;
            }
            __syncthreads();
            LI = s_li;
            if (LI >= 0 || --c < 0) break;
        }

        if (LI >= 0) {
            // fp64 exclusive prefix of chunk sums [0, c)
            double p = 0.0;
            for (int j = threadIdx.x; j < c; j += SEGBLK) p += (double)csums[j];
            p = waveReduceSumD(p);
            if (lane == 0) redD[wid] = p;

            // fp32 in-chunk exp-sum up to and including LI
            const int base = c << CHUNK_LOG;
            float fs = 0.f;
            for (int i = base + (int)threadIdx.x; i <= LI; i += SEGBLK)
                fs += __expf(outs[i]);
            fs = waveReduceSumF(fs);
            if (lane == 0) redF[wid] = fs;
            __syncthreads();
            if (threadIdx.x == 0) {
                double pre = 0.0;
                float fsum = 0.f;
#pragma unroll
                for (int j = 0; j < SEGBLK / 64; ++j) { pre += redD[j]; fsum += redF[j]; }
                double sm = log(pre + (double)fsum);  // monotone cumsum => max at LI
                if (sm < 0.0) sm = 0.0;               // jnp.maximum(..., 0.0)
                atomicAdd(loss2, sm * (double)cnt);
            }
        }
    }

    // done-ticket: last block finalizes (no separate final kernel)
    if (threadIdx.x == 0) {
        __threadfence();
        const unsigned d = atomicAdd(done, 1u);
        if (d == (unsigned)(gridDim.x - 1)) {
            const double l2 = atomicAdd(loss2, 0.0);            // atomic read
            const double l1 = *(volatile const double*)loss1;   // prior dispatch
            const unsigned o = *(volatile const unsigned*)obs;
            out[0] = (float)((l2 - l1) / (double)o);
        }
    }
}

extern "C" void kernel_launch(void* const* d_in, const int* in_sizes, int n_in,
                              void* d_out, int out_size, void* d_ws, size_t ws_size,
                              hipStream_t stream) {
    const float* outs = (const float*)d_in[0];
    const int* te = (const int*)d_in[1];
    const int* tt = (const int*)d_in[2];
    const int N = in_sizes[0];
    float* out = (float*)d_out;

    const int nChunks = (N + CHUNK - 1) / CHUNK;

    char* ws = (char*)d_ws;
    double* d_loss1 = (double*)ws;                        // 1 double
    double* d_loss2 = d_loss1 + 1;                        // 1 double
    float* d_csums = (float*)(ws + 16);                   // nChunks floats
    unsigned* d_segcnt = (unsigned*)(d_csums + nChunks);  // NUM_SEGS u32
    unsigned* d_obs = d_segcnt + NUM_SEGS;
    unsigned* d_done = d_obs + 1;

    const int initThreads = (nChunks > NUM_SEGS ? nChunks : NUM_SEGS);
    init_kernel<<<(initThreads + 255) / 256, 256, 0, stream>>>(
        d_segcnt, d_csums, nChunks, d_obs, d_loss1, d_loss2, d_done);
    const int nSuper = (N + SUPER - 1) / SUPER;
    pass1_kernel<<<nSuper, BLK, 0, stream>>>(outs, te, tt, N, nChunks, d_csums,
                                             d_segcnt, d_obs, d_loss1);
    seg_final_kernel<<<NUM_SEGS, SEGBLK, 0, stream>>>(
        outs, tt, d_csums, d_segcnt, d_loss1, d_loss2, d_obs, d_done, out, N,
        nChunks);
}